// Round 5
// baseline (231.245 us; speedup 1.0000x reference)
//
#include <hip/hip_runtime.h>
#include <math.h>

#define DELTA_V 0.5f
#define DELTA_D 3.0f
#define P_REG   0.001f

#define TPB    256
#define BIN_B  128   // blocks per binary slice,  GR=4: 128*256*4 = 131072 groups
#define INST_B 256   // blocks per instance slice, GR=2: 256*256*2 = 131072 groups
#define NBLK   (4 * BIN_B + 4 * INST_B)   // 1536
#define NVMAX  36
#define SLOTS  256   // partial slots per slice (max of BIN_B/INST_B)

// workspace layout (float offsets). no counters, no memset: kernel boundaries
// provide device-scope release/acquire (fences inside kernels cost a full
// per-XCD L2 writeback each -- measured 2x slowdown in R4).
#define P1_OFF   0                           // [8][SLOTS][NVMAX]
#define CNT_OFF  (8 * SLOTS * NVMAX)         // [8][6]
#define MEAN_OFF (CNT_OFF + 48)              // [8][30]
#define LDR_OFF  (MEAN_OFF + 240)            // [8]
#define P2_OFF   (LDR_OFF + 8)               // [8][SLOTS][6]

__device__ __forceinline__ void block_map(int bx, int& s, int& j, int& NB) {
    if (bx < 4 * BIN_B) { s = bx >> 7; j = bx & (BIN_B - 1); NB = BIN_B; }
    else { int q = bx - 4 * BIN_B; s = 4 + (q >> 8); j = q & (INST_B - 1); NB = INST_B; }
}

// ---------------- Pass 1 body: per-label counts and sums ----------------
// GR groups per thread, all loads issued straight-line before compute.
template<int K, int D, int GR>
__device__ void pass1_body(const float* __restrict__ pred,   // [D][MN] this batch
                           const int*  __restrict__ labels,  // [MN]
                           float* __restrict__ partials,     // this block's [NVMAX] slot
                           int n4, int j, int NB, float (*lredW)[NVMAX]) {
    constexpr int NV = K * (D + 1);
    const float4* pred4 = (const float4*)pred;
    const int4*   lab4  = (const int4*)labels;
    const int g0     = j * TPB + threadIdx.x;
    const int stride = NB * TPB;

    int4   lv[GR];
    float4 xv[GR][D];
    #pragma unroll
    for (int c = 0; c < GR; ++c) {
        const int i = g0 + c * stride;
        if (i < n4) {
            lv[c] = lab4[i];
            #pragma unroll
            for (int d = 0; d < D; ++d) xv[c][d] = pred4[(size_t)d * n4 + i];
        } else {
            lv[c] = make_int4(-1, -1, -1, -1);
            #pragma unroll
            for (int d = 0; d < D; ++d) xv[c][d] = make_float4(0.f, 0.f, 0.f, 0.f);
        }
    }

    float acc[K][D + 1];
    #pragma unroll
    for (int k = 0; k < K; ++k)
        #pragma unroll
        for (int jj = 0; jj <= D; ++jj) acc[k][jj] = 0.f;

    #pragma unroll
    for (int c = 0; c < GR; ++c) {
        const int labs[4] = {lv[c].x, lv[c].y, lv[c].z, lv[c].w};
        const float* xs = (const float*)&xv[c][0];   // xs[d*4 + p]
        #pragma unroll
        for (int p = 0; p < 4; ++p) {
            const int lab = labs[p];
            #pragma unroll
            for (int k = 0; k < K; ++k) {
                const float ind = (lab == k) ? 1.f : 0.f;
                acc[k][D] += ind;
                #pragma unroll
                for (int d = 0; d < D; ++d)
                    acc[k][d] = fmaf(ind, xs[d * 4 + p], acc[k][d]);
            }
        }
    }

    const int wave = threadIdx.x >> 6, lane = threadIdx.x & 63;
    #pragma unroll
    for (int k = 0; k < K; ++k) {
        #pragma unroll
        for (int jj = 0; jj <= D; ++jj) {
            float v = acc[k][jj];
            for (int off = 32; off > 0; off >>= 1) v += __shfl_down(v, off);
            if (lane == 0) lredW[wave][k * (D + 1) + jj] = v;
        }
    }
    __syncthreads();
    if (threadIdx.x < NV) {
        const int t = threadIdx.x;
        partials[t] = lredW[0][t] + lredW[1][t] + lredW[2][t] + lredW[3][t];
    }
}

__global__ __launch_bounds__(TPB)
void pass1_fused(const float* __restrict__ bl, const int* __restrict__ bL,
                 const float* __restrict__ il, const int* __restrict__ iL,
                 float* __restrict__ ws, int MN) {
    int s, j, NB;
    block_map(blockIdx.x, s, j, NB);
    const int b = s & 3;
    const int n4 = MN >> 2;
    __shared__ float lredW[4][NVMAX];
    float* partials = ws + P1_OFF + (size_t)(s * SLOTS + j) * NVMAX;
    if (s < 4) pass1_body<2, 2, 4>(bl + (size_t)b * 2 * MN, bL + (size_t)b * MN, partials, n4, j, NB, lredW);
    else       pass1_body<6, 5, 2>(il + (size_t)b * 5 * MN, iL + (size_t)b * MN, partials, n4, j, NB, lredW);
}

// ---------------- Mid: reduce partials -> cnt/means, push(dist)+reg ----------------
__global__ void mid_kernel(float* __restrict__ ws) {
    const int s = blockIdx.x;
    const int isInst = s >> 2;
    const int K = isInst ? 6 : 2, D = isInst ? 5 : 2;
    const int NB = isInst ? INST_B : BIN_B;
    const int NV = K * (D + 1);
    const float* P = ws + P1_OFF + (size_t)s * SLOTS * NVMAX;
    const int t = threadIdx.x;
    __shared__ float tot[NVMAX];
    __shared__ float muS[30];
    __shared__ float cntS[6];
    if (t < NV) {
        float v = 0.f;
        for (int jj = 0; jj < NB; ++jj) v += P[jj * NVMAX + t];
        tot[t] = v;
        const int k = t / (D + 1), r = t % (D + 1);
        if (r == D) { cntS[k] = v; ws[CNT_OFF + s * 6 + k] = v; }
    }
    __syncthreads();
    if (t < NV) {
        const int k = t / (D + 1), r = t % (D + 1);
        if (r < D) {
            const float m = tot[t] / cntS[k];
            muS[k * D + r] = m;
            ws[MEAN_OFF + s * 30 + k * D + r] = m;
        }
    }
    __syncthreads();
    if (t == 0) {
        float l_dist = 0.f, l_reg = 0.f;
        for (int i = 0; i < K; ++i) {
            float n2 = 0.f;
            for (int d = 0; d < D; ++d) n2 += muS[i * D + d] * muS[i * D + d];
            l_reg += sqrtf(n2);
            for (int jj = 0; jj < K; ++jj) {
                if (i == jj) continue;
                float sq = 0.f;
                for (int d = 0; d < D; ++d) { const float df = muS[i * D + d] - muS[jj * D + d]; sq += df * df; }
                const float dn = fmaxf(2.f * DELTA_D - sqrtf(sq), 0.f);
                l_dist += dn * dn;
            }
        }
        l_dist /= (float)(K * (K - 1));
        l_reg  /= (float)K;
        ws[LDR_OFF + s] = l_dist + P_REG * l_reg;
    }
}

// ---------------- Pass 2 body: hinged variance ----------------
template<int K, int D, int GR>
__device__ void pass2_body(const float* __restrict__ pred,
                           const int*  __restrict__ labels,
                           const float* __restrict__ means,   // [K*D]
                           float* __restrict__ partials,      // this block's [6] slot
                           int n4, int j, int NB, float* mu, float (*lredW)[6]) {
    if (threadIdx.x < K * D) mu[threadIdx.x] = means[threadIdx.x];
    __syncthreads();

    const float4* pred4 = (const float4*)pred;
    const int4*   lab4  = (const int4*)labels;
    const int g0     = j * TPB + threadIdx.x;
    const int stride = NB * TPB;

    int4   lv[GR];
    float4 xv[GR][D];
    #pragma unroll
    for (int c = 0; c < GR; ++c) {
        const int i = g0 + c * stride;
        if (i < n4) {
            lv[c] = lab4[i];
            #pragma unroll
            for (int d = 0; d < D; ++d) xv[c][d] = pred4[(size_t)d * n4 + i];
        } else {
            lv[c] = make_int4(-1, -1, -1, -1);
            #pragma unroll
            for (int d = 0; d < D; ++d) xv[c][d] = make_float4(0.f, 0.f, 0.f, 0.f);
        }
    }

    float acc[K];
    #pragma unroll
    for (int k = 0; k < K; ++k) acc[k] = 0.f;

    #pragma unroll
    for (int c = 0; c < GR; ++c) {
        const int labs[4] = {lv[c].x, lv[c].y, lv[c].z, lv[c].w};
        const float* xs = (const float*)&xv[c][0];
        #pragma unroll
        for (int p = 0; p < 4; ++p) {
            const int lab = labs[p];
            const int li = lab < 0 ? 0 : lab;
            float sq = 0.f;
            #pragma unroll
            for (int d = 0; d < D; ++d) {
                const float df = mu[li * D + d] - xs[d * 4 + p];
                sq = fmaf(df, df, sq);
            }
            const float h = fmaxf(sqrtf(sq) - DELTA_V, 0.f);
            const float h2 = h * h;
            #pragma unroll
            for (int k = 0; k < K; ++k)
                acc[k] += (lab == k) ? h2 : 0.f;
        }
    }

    const int wave = threadIdx.x >> 6, lane = threadIdx.x & 63;
    #pragma unroll
    for (int k = 0; k < K; ++k) {
        float v = acc[k];
        for (int off = 32; off > 0; off >>= 1) v += __shfl_down(v, off);
        if (lane == 0) lredW[wave][k] = v;
    }
    __syncthreads();
    if (threadIdx.x < K) {
        const int t = threadIdx.x;
        partials[t] = lredW[0][t] + lredW[1][t] + lredW[2][t] + lredW[3][t];
    }
}

__global__ __launch_bounds__(TPB)
void pass2_fused(const float* __restrict__ bl, const int* __restrict__ bL,
                 const float* __restrict__ il, const int* __restrict__ iL,
                 float* __restrict__ ws, int MN) {
    int s, j, NB;
    block_map(blockIdx.x, s, j, NB);
    const int b = s & 3;
    const int n4 = MN >> 2;
    __shared__ float mu[30];
    __shared__ float lredW[4][6];
    const float* means = ws + MEAN_OFF + s * 30;
    float* partials = ws + P2_OFF + (size_t)(s * SLOTS + j) * 6;
    if (s < 4) pass2_body<2, 2, 4>(bl + (size_t)b * 2 * MN, bL + (size_t)b * MN, means, partials, n4, j, NB, mu, lredW);
    else       pass2_body<6, 5, 2>(il + (size_t)b * 5 * MN, iL + (size_t)b * MN, means, partials, n4, j, NB, mu, lredW);
}

// ---------------- Final: fold into 2 scalars ----------------
__global__ void final_kernel(const float* __restrict__ ws, float* __restrict__ out) {
    __shared__ float contrib[48];
    const int t = threadIdx.x;
    if (t < 48) {
        const int s2 = t / 6, k = t % 6;
        const int Ks  = (s2 < 4) ? 2 : 6;
        const int NBs = (s2 < 4) ? BIN_B : INST_B;
        float c = 0.f;
        if (k < Ks) {
            const float* P = ws + P2_OFF + (size_t)s2 * SLOTS * 6;
            float v = 0.f;
            for (int jj = 0; jj < NBs; ++jj) v += P[jj * 6 + k];
            c = v / ws[CNT_OFF + s2 * 6 + k];
        }
        contrib[t] = c;
    }
    __syncthreads();
    if (t == 0) {
        float totB = 0.f, totI = 0.f;
        for (int s2 = 0; s2 < 8; ++s2) {
            const int Ks = (s2 < 4) ? 2 : 6;
            float lv = 0.f;
            for (int k = 0; k < Ks; ++k) lv += contrib[s2 * 6 + k];
            lv /= (float)Ks;
            const float loss = lv + ws[LDR_OFF + s2];
            if (s2 < 4) totB += loss; else totI += loss;
        }
        out[0] = totB * 0.25f;
        out[1] = totI * 0.25f;
    }
}

extern "C" void kernel_launch(void* const* d_in, const int* in_sizes, int n_in,
                              void* d_out, int out_size, void* d_ws, size_t ws_size,
                              hipStream_t stream) {
    const float* bin_logits  = (const float*)d_in[0];
    const int*   bin_labels  = (const int*)d_in[1];
    const float* inst_logits = (const float*)d_in[2];
    const int*   inst_labels = (const int*)d_in[3];
    float* ws  = (float*)d_ws;
    float* out = (float*)d_out;

    const int B  = 4;
    const int MN = in_sizes[1] / B;   // 524288

    pass1_fused<<<NBLK, TPB, 0, stream>>>(bin_logits, bin_labels, inst_logits, inst_labels, ws, MN);
    mid_kernel<<<8, 64, 0, stream>>>(ws);
    pass2_fused<<<NBLK, TPB, 0, stream>>>(bin_logits, bin_labels, inst_logits, inst_labels, ws, MN);
    final_kernel<<<1, 64, 0, stream>>>(ws, out);
}

// Round 6
// 158.184 us; speedup vs baseline: 1.4619x; 1.4619x over previous
//
#include <hip/hip_runtime.h>
#include <math.h>

#define DELTA_V 0.5f
#define DELTA_D 3.0f
#define P_REG   0.001f

#define TPB    256
#define BIN_B  128   // blocks per binary slice,  GR=4: 128*256*4 = 131072 groups
#define INST_B 256   // blocks per instance slice, GR=2: 256*256*2 = 131072 groups
#define NBLK   (4 * BIN_B + 4 * INST_B)   // 1536
#define NVMAX  36
#define SLOTS  256   // partial slots per slice (max of BIN_B/INST_B)

// workspace layout (float offsets). no fences: kernel boundaries provide
// device-scope release/acquire (in-kernel agent fences = L2 writeback, R4: 2x slower).
#define P1_OFF   0                           // [8][SLOTS][NVMAX]
#define CNT_OFF  (8 * SLOTS * NVMAX)         // [8][6]
#define MEAN_OFF (CNT_OFF + 48)              // [8][30]
#define LDR_OFF  (MEAN_OFF + 240)            // [8]
#define P2_OFF   (LDR_OFF + 8)               // [8][SLOTS][6]

__device__ __forceinline__ void block_map(int bx, int& s, int& j, int& NB) {
    if (bx < 4 * BIN_B) { s = bx >> 7; j = bx & (BIN_B - 1); NB = BIN_B; }
    else { int q = bx - 4 * BIN_B; s = 4 + (q >> 8); j = q & (INST_B - 1); NB = INST_B; }
}

// ---------------- Pass 1 body: per-label counts and sums ----------------
template<int K, int D, int GR>
__device__ void pass1_body(const float* __restrict__ pred,   // [D][MN] this batch
                           const int*  __restrict__ labels,  // [MN]
                           float* __restrict__ partials,     // this block's [NVMAX] slot
                           int n4, int j, int NB, float (*lredW)[NVMAX]) {
    constexpr int NV = K * (D + 1);
    const float4* pred4 = (const float4*)pred;
    const int4*   lab4  = (const int4*)labels;
    const int g0     = j * TPB + threadIdx.x;
    const int stride = NB * TPB;

    int4   lv[GR];
    float4 xv[GR][D];
    #pragma unroll
    for (int c = 0; c < GR; ++c) {
        const int i = g0 + c * stride;
        if (i < n4) {
            lv[c] = lab4[i];
            #pragma unroll
            for (int d = 0; d < D; ++d) xv[c][d] = pred4[(size_t)d * n4 + i];
        } else {
            lv[c] = make_int4(-1, -1, -1, -1);
            #pragma unroll
            for (int d = 0; d < D; ++d) xv[c][d] = make_float4(0.f, 0.f, 0.f, 0.f);
        }
    }

    float acc[K][D + 1];
    #pragma unroll
    for (int k = 0; k < K; ++k)
        #pragma unroll
        for (int jj = 0; jj <= D; ++jj) acc[k][jj] = 0.f;

    #pragma unroll
    for (int c = 0; c < GR; ++c) {
        const int labs[4] = {lv[c].x, lv[c].y, lv[c].z, lv[c].w};
        const float* xs = (const float*)&xv[c][0];   // xs[d*4 + p]
        #pragma unroll
        for (int p = 0; p < 4; ++p) {
            const int lab = labs[p];
            #pragma unroll
            for (int k = 0; k < K; ++k) {
                const float ind = (lab == k) ? 1.f : 0.f;
                acc[k][D] += ind;
                #pragma unroll
                for (int d = 0; d < D; ++d)
                    acc[k][d] = fmaf(ind, xs[d * 4 + p], acc[k][d]);
            }
        }
    }

    const int wave = threadIdx.x >> 6, lane = threadIdx.x & 63;
    #pragma unroll
    for (int k = 0; k < K; ++k) {
        #pragma unroll
        for (int jj = 0; jj <= D; ++jj) {
            float v = acc[k][jj];
            for (int off = 32; off > 0; off >>= 1) v += __shfl_down(v, off);
            if (lane == 0) lredW[wave][k * (D + 1) + jj] = v;
        }
    }
    __syncthreads();
    if (threadIdx.x < NV) {
        const int t = threadIdx.x;
        partials[t] = lredW[0][t] + lredW[1][t] + lredW[2][t] + lredW[3][t];
    }
}

__global__ __launch_bounds__(TPB)
void pass1_fused(const float* __restrict__ bl, const int* __restrict__ bL,
                 const float* __restrict__ il, const int* __restrict__ iL,
                 float* __restrict__ ws, int MN) {
    int s, j, NB;
    block_map(blockIdx.x, s, j, NB);
    const int b = s & 3;
    const int n4 = MN >> 2;
    __shared__ float lredW[4][NVMAX];
    float* partials = ws + P1_OFF + (size_t)(s * SLOTS + j) * NVMAX;
    if (s < 4) pass1_body<2, 2, 4>(bl + (size_t)b * 2 * MN, bL + (size_t)b * MN, partials, n4, j, NB, lredW);
    else       pass1_body<6, 5, 2>(il + (size_t)b * 5 * MN, iL + (size_t)b * MN, partials, n4, j, NB, lredW);
}

// ---------------- Mid: slot-parallel reduce -> cnt/means, push(dist)+reg ----------------
__global__ __launch_bounds__(TPB)
void mid_kernel(float* __restrict__ ws) {
    const int s = blockIdx.x;
    const int isInst = s >> 2;
    const int K = isInst ? 6 : 2, D = isInst ? 5 : 2;
    const int NB = isInst ? INST_B : BIN_B;
    const int NV = K * (D + 1);
    const int jj = threadIdx.x;
    const float* P = ws + P1_OFF + (size_t)s * SLOTS * NVMAX;

    // each thread owns one slot: 9 independent float4 loads (slot stride 144 B, 16-B aligned)
    float acc[NVMAX];
    if (jj < NB) {
        const float4* p4 = (const float4*)(P + (size_t)jj * NVMAX);
        #pragma unroll
        for (int q = 0; q < 9; ++q) {
            const float4 v = p4[q];
            acc[q * 4 + 0] = v.x; acc[q * 4 + 1] = v.y;
            acc[q * 4 + 2] = v.z; acc[q * 4 + 3] = v.w;
        }
    } else {
        #pragma unroll
        for (int t = 0; t < NVMAX; ++t) acc[t] = 0.f;
    }

    __shared__ float lredW[4][NVMAX];
    const int wave = jj >> 6, lane = jj & 63;
    #pragma unroll
    for (int t = 0; t < NVMAX; ++t) {
        float v = acc[t];
        for (int off = 32; off > 0; off >>= 1) v += __shfl_down(v, off);
        if (lane == 0) lredW[wave][t] = v;
    }
    __syncthreads();

    __shared__ float tot[NVMAX];
    __shared__ float muS[30];
    __shared__ float cntS[6];
    const int t = threadIdx.x;
    if (t < NV) {
        const float v = lredW[0][t] + lredW[1][t] + lredW[2][t] + lredW[3][t];
        tot[t] = v;
        const int k = t / (D + 1), r = t % (D + 1);
        if (r == D) { cntS[k] = v; ws[CNT_OFF + s * 6 + k] = v; }
    }
    __syncthreads();
    if (t < NV) {
        const int k = t / (D + 1), r = t % (D + 1);
        if (r < D) {
            const float m = tot[t] / cntS[k];
            muS[k * D + r] = m;
            ws[MEAN_OFF + s * 30 + k * D + r] = m;
        }
    }
    __syncthreads();
    if (t == 0) {
        float l_dist = 0.f, l_reg = 0.f;
        for (int i = 0; i < K; ++i) {
            float n2 = 0.f;
            for (int d = 0; d < D; ++d) n2 += muS[i * D + d] * muS[i * D + d];
            l_reg += sqrtf(n2);
            for (int q = 0; q < K; ++q) {
                if (i == q) continue;
                float sq = 0.f;
                for (int d = 0; d < D; ++d) { const float df = muS[i * D + d] - muS[q * D + d]; sq += df * df; }
                const float dn = fmaxf(2.f * DELTA_D - sqrtf(sq), 0.f);
                l_dist += dn * dn;
            }
        }
        l_dist /= (float)(K * (K - 1));
        l_reg  /= (float)K;
        ws[LDR_OFF + s] = l_dist + P_REG * l_reg;
    }
}

// ---------------- Pass 2 body: hinged variance ----------------
template<int K, int D, int GR>
__device__ void pass2_body(const float* __restrict__ pred,
                           const int*  __restrict__ labels,
                           const float* __restrict__ means,   // [K*D]
                           float* __restrict__ partials,      // this block's [6] slot
                           int n4, int j, int NB, float* mu, float (*lredW)[6]) {
    if (threadIdx.x < K * D) mu[threadIdx.x] = means[threadIdx.x];
    __syncthreads();

    const float4* pred4 = (const float4*)pred;
    const int4*   lab4  = (const int4*)labels;
    const int g0     = j * TPB + threadIdx.x;
    const int stride = NB * TPB;

    int4   lv[GR];
    float4 xv[GR][D];
    #pragma unroll
    for (int c = 0; c < GR; ++c) {
        const int i = g0 + c * stride;
        if (i < n4) {
            lv[c] = lab4[i];
            #pragma unroll
            for (int d = 0; d < D; ++d) xv[c][d] = pred4[(size_t)d * n4 + i];
        } else {
            lv[c] = make_int4(-1, -1, -1, -1);
            #pragma unroll
            for (int d = 0; d < D; ++d) xv[c][d] = make_float4(0.f, 0.f, 0.f, 0.f);
        }
    }

    float acc[K];
    #pragma unroll
    for (int k = 0; k < K; ++k) acc[k] = 0.f;

    #pragma unroll
    for (int c = 0; c < GR; ++c) {
        const int labs[4] = {lv[c].x, lv[c].y, lv[c].z, lv[c].w};
        const float* xs = (const float*)&xv[c][0];
        #pragma unroll
        for (int p = 0; p < 4; ++p) {
            const int lab = labs[p];
            const int li = lab < 0 ? 0 : lab;
            float sq = 0.f;
            #pragma unroll
            for (int d = 0; d < D; ++d) {
                const float df = mu[li * D + d] - xs[d * 4 + p];
                sq = fmaf(df, df, sq);
            }
            const float h = fmaxf(sqrtf(sq) - DELTA_V, 0.f);
            const float h2 = h * h;
            #pragma unroll
            for (int k = 0; k < K; ++k)
                acc[k] += (lab == k) ? h2 : 0.f;
        }
    }

    const int wave = threadIdx.x >> 6, lane = threadIdx.x & 63;
    #pragma unroll
    for (int k = 0; k < K; ++k) {
        float v = acc[k];
        for (int off = 32; off > 0; off >>= 1) v += __shfl_down(v, off);
        if (lane == 0) lredW[wave][k] = v;
    }
    __syncthreads();
    if (threadIdx.x < K) {
        const int t = threadIdx.x;
        partials[t] = lredW[0][t] + lredW[1][t] + lredW[2][t] + lredW[3][t];
    }
}

__global__ __launch_bounds__(TPB)
void pass2_fused(const float* __restrict__ bl, const int* __restrict__ bL,
                 const float* __restrict__ il, const int* __restrict__ iL,
                 float* __restrict__ ws, int MN) {
    int s, j, NB;
    block_map(blockIdx.x, s, j, NB);
    const int b = s & 3;
    const int n4 = MN >> 2;
    __shared__ float mu[30];
    __shared__ float lredW[4][6];
    const float* means = ws + MEAN_OFF + s * 30;
    float* partials = ws + P2_OFF + (size_t)(s * SLOTS + j) * 6;
    if (s < 4) pass2_body<2, 2, 4>(bl + (size_t)b * 2 * MN, bL + (size_t)b * MN, means, partials, n4, j, NB, mu, lredW);
    else       pass2_body<6, 5, 2>(il + (size_t)b * 5 * MN, iL + (size_t)b * MN, means, partials, n4, j, NB, mu, lredW);
}

// ---------------- Final: slot-parallel fold into 2 scalars ----------------
__global__ __launch_bounds__(TPB)
void final_kernel(const float* __restrict__ ws, float* __restrict__ out) {
    const int jj = threadIdx.x;
    const int wave = jj >> 6, lane = jj & 63;

    // preload: 48 independent scalar loads (8 slices x 6 vals from this thread's slot)
    float a[8][6];
    #pragma unroll
    for (int s2 = 0; s2 < 8; ++s2) {
        const int NBs = (s2 < 4) ? BIN_B : INST_B;
        const float* P = ws + P2_OFF + (size_t)s2 * SLOTS * 6 + (size_t)jj * 6;
        #pragma unroll
        for (int k = 0; k < 6; ++k) a[s2][k] = (jj < NBs) ? P[k] : 0.f;
    }

    __shared__ float lredW[4][8][6];
    #pragma unroll
    for (int s2 = 0; s2 < 8; ++s2) {
        #pragma unroll
        for (int k = 0; k < 6; ++k) {
            float v = a[s2][k];
            for (int off = 32; off > 0; off >>= 1) v += __shfl_down(v, off);
            if (lane == 0) lredW[wave][s2][k] = v;
        }
    }
    __syncthreads();

    if (jj == 0) {
        float totB = 0.f, totI = 0.f;
        for (int s2 = 0; s2 < 8; ++s2) {
            const int Ks = (s2 < 4) ? 2 : 6;
            float lv = 0.f;
            for (int k = 0; k < Ks; ++k) {
                const float v = lredW[0][s2][k] + lredW[1][s2][k] + lredW[2][s2][k] + lredW[3][s2][k];
                lv += v / ws[CNT_OFF + s2 * 6 + k];
            }
            lv /= (float)Ks;
            const float loss = lv + ws[LDR_OFF + s2];
            if (s2 < 4) totB += loss; else totI += loss;
        }
        out[0] = totB * 0.25f;
        out[1] = totI * 0.25f;
    }
}

extern "C" void kernel_launch(void* const* d_in, const int* in_sizes, int n_in,
                              void* d_out, int out_size, void* d_ws, size_t ws_size,
                              hipStream_t stream) {
    const float* bin_logits  = (const float*)d_in[0];
    const int*   bin_labels  = (const int*)d_in[1];
    const float* inst_logits = (const float*)d_in[2];
    const int*   inst_labels = (const int*)d_in[3];
    float* ws  = (float*)d_ws;
    float* out = (float*)d_out;

    const int B  = 4;
    const int MN = in_sizes[1] / B;   // 524288

    pass1_fused<<<NBLK, TPB, 0, stream>>>(bin_logits, bin_labels, inst_logits, inst_labels, ws, MN);
    mid_kernel<<<8, TPB, 0, stream>>>(ws);
    pass2_fused<<<NBLK, TPB, 0, stream>>>(bin_logits, bin_labels, inst_logits, inst_labels, ws, MN);
    final_kernel<<<1, TPB, 0, stream>>>(ws, out);
}

// Round 7
// 155.073 us; speedup vs baseline: 1.4912x; 1.0201x over previous
//
#include <hip/hip_runtime.h>
#include <math.h>

#define DELTA_V 0.5f
#define DELTA_D 3.0f
#define P_REG   0.001f

#define TPB    256
#define BPS    128   // blocks per slice; 131072 groups / (128*256) = 4 iters/thread, exact
#define NBLK   (8 * BPS)   // 1024
#define LOOPS  4
#define NVMAX  36
#define SLOTS  128

// workspace layout (float offsets). no fences: kernel boundaries provide
// device-scope release/acquire (in-kernel agent fences = L2 writeback, R4: 2x slower).
// serial reduction loops are poison (R5: 74 us mid) -- mid/final are slot-parallel.
#define P1_OFF   0                           // [8][SLOTS][NVMAX]
#define CNT_OFF  (8 * SLOTS * NVMAX)         // [8][6]
#define MEAN_OFF (CNT_OFF + 48)              // [8][30]
#define LDR_OFF  (MEAN_OFF + 240)            // [8]
#define P2_OFF   (LDR_OFF + 8)               // [8][SLOTS][6]

// ---------------- Pass 1 body: per-label counts and sums ----------------
// compile-time trip count, no guards: compiler unrolls + software-pipelines.
template<int K, int D>
__device__ void pass1_body(const float* __restrict__ pred,   // [D][MN] this batch
                           const int*  __restrict__ labels,  // [MN]
                           float* __restrict__ partials,     // this block's [NVMAX] slot
                           int n4, float (*lredW)[NVMAX]) {
    constexpr int NV = K * (D + 1);
    const float4* pred4 = (const float4*)pred;
    const int4*   lab4  = (const int4*)labels;
    const int g0     = blockIdx.x % BPS * TPB + threadIdx.x;
    const int stride = BPS * TPB;

    float acc[K][D + 1];
    #pragma unroll
    for (int k = 0; k < K; ++k)
        #pragma unroll
        for (int jj = 0; jj <= D; ++jj) acc[k][jj] = 0.f;

    #pragma unroll
    for (int c = 0; c < LOOPS; ++c) {
        const int i = g0 + c * stride;
        const int4 lv = lab4[i];
        float4 xv[D];
        #pragma unroll
        for (int d = 0; d < D; ++d) xv[d] = pred4[(size_t)d * n4 + i];
        const int labs[4] = {lv.x, lv.y, lv.z, lv.w};
        const float* xs = (const float*)&xv[0];   // xs[d*4 + p]
        #pragma unroll
        for (int p = 0; p < 4; ++p) {
            const int lab = labs[p];
            #pragma unroll
            for (int k = 0; k < K; ++k) {
                const float ind = (lab == k) ? 1.f : 0.f;
                acc[k][D] += ind;
                #pragma unroll
                for (int d = 0; d < D; ++d)
                    acc[k][d] = fmaf(ind, xs[d * 4 + p], acc[k][d]);
            }
        }
    }

    const int wave = threadIdx.x >> 6, lane = threadIdx.x & 63;
    #pragma unroll
    for (int k = 0; k < K; ++k) {
        #pragma unroll
        for (int jj = 0; jj <= D; ++jj) {
            float v = acc[k][jj];
            for (int off = 32; off > 0; off >>= 1) v += __shfl_down(v, off);
            if (lane == 0) lredW[wave][k * (D + 1) + jj] = v;
        }
    }
    __syncthreads();
    if (threadIdx.x < NV) {
        const int t = threadIdx.x;
        partials[t] = lredW[0][t] + lredW[1][t] + lredW[2][t] + lredW[3][t];
    }
}

__global__ __launch_bounds__(TPB)
void pass1_fused(const float* __restrict__ bl, const int* __restrict__ bL,
                 const float* __restrict__ il, const int* __restrict__ iL,
                 float* __restrict__ ws, int MN) {
    const int s = blockIdx.x / BPS, j = blockIdx.x % BPS;
    const int b = s & 3;
    const int n4 = MN >> 2;
    __shared__ float lredW[4][NVMAX];
    float* partials = ws + P1_OFF + (size_t)(s * SLOTS + j) * NVMAX;
    if (s < 4) pass1_body<2, 2>(bl + (size_t)b * 2 * MN, bL + (size_t)b * MN, partials, n4, lredW);
    else       pass1_body<6, 5>(il + (size_t)b * 5 * MN, iL + (size_t)b * MN, partials, n4, lredW);
}

// ---------------- Mid: slot-parallel reduce -> cnt/means, push(dist)+reg ----------------
__global__ __launch_bounds__(TPB)
void mid_kernel(float* __restrict__ ws) {
    const int s = blockIdx.x;
    const int isInst = s >> 2;
    const int K = isInst ? 6 : 2, D = isInst ? 5 : 2;
    const int NV = K * (D + 1);
    const int jj = threadIdx.x;
    const float* P = ws + P1_OFF + (size_t)s * SLOTS * NVMAX;

    // each thread owns one slot: 9 independent float4 loads (slot stride 144 B, 16-B aligned)
    float acc[NVMAX];
    if (jj < SLOTS) {
        const float4* p4 = (const float4*)(P + (size_t)jj * NVMAX);
        #pragma unroll
        for (int q = 0; q < 9; ++q) {
            const float4 v = p4[q];
            acc[q * 4 + 0] = v.x; acc[q * 4 + 1] = v.y;
            acc[q * 4 + 2] = v.z; acc[q * 4 + 3] = v.w;
        }
    } else {
        #pragma unroll
        for (int t = 0; t < NVMAX; ++t) acc[t] = 0.f;
    }

    __shared__ float lredW[4][NVMAX];
    const int wave = jj >> 6, lane = jj & 63;
    #pragma unroll
    for (int t = 0; t < NVMAX; ++t) {
        float v = acc[t];
        for (int off = 32; off > 0; off >>= 1) v += __shfl_down(v, off);
        if (lane == 0) lredW[wave][t] = v;
    }
    __syncthreads();

    __shared__ float tot[NVMAX];
    __shared__ float muS[30];
    __shared__ float cntS[6];
    const int t = threadIdx.x;
    if (t < NV) {
        const float v = lredW[0][t] + lredW[1][t] + lredW[2][t] + lredW[3][t];
        tot[t] = v;
        const int k = t / (D + 1), r = t % (D + 1);
        if (r == D) { cntS[k] = v; ws[CNT_OFF + s * 6 + k] = v; }
    }
    __syncthreads();
    if (t < NV) {
        const int k = t / (D + 1), r = t % (D + 1);
        if (r < D) {
            const float m = tot[t] / cntS[k];
            muS[k * D + r] = m;
            ws[MEAN_OFF + s * 30 + k * D + r] = m;
        }
    }
    __syncthreads();
    if (t == 0) {
        float l_dist = 0.f, l_reg = 0.f;
        for (int i = 0; i < K; ++i) {
            float n2 = 0.f;
            for (int d = 0; d < D; ++d) n2 += muS[i * D + d] * muS[i * D + d];
            l_reg += sqrtf(n2);
            for (int q = 0; q < K; ++q) {
                if (i == q) continue;
                float sq = 0.f;
                for (int d = 0; d < D; ++d) { const float df = muS[i * D + d] - muS[q * D + d]; sq += df * df; }
                const float dn = fmaxf(2.f * DELTA_D - sqrtf(sq), 0.f);
                l_dist += dn * dn;
            }
        }
        l_dist /= (float)(K * (K - 1));
        l_reg  /= (float)K;
        ws[LDR_OFF + s] = l_dist + P_REG * l_reg;
    }
}

// ---------------- Pass 2 body: hinged variance ----------------
template<int K, int D>
__device__ void pass2_body(const float* __restrict__ pred,
                           const int*  __restrict__ labels,
                           const float* __restrict__ means,   // [K*D]
                           float* __restrict__ partials,      // this block's [6] slot
                           int n4, float* mu, float (*lredW)[6]) {
    if (threadIdx.x < K * D) mu[threadIdx.x] = means[threadIdx.x];
    __syncthreads();

    const float4* pred4 = (const float4*)pred;
    const int4*   lab4  = (const int4*)labels;
    const int g0     = blockIdx.x % BPS * TPB + threadIdx.x;
    const int stride = BPS * TPB;

    float acc[K];
    #pragma unroll
    for (int k = 0; k < K; ++k) acc[k] = 0.f;

    #pragma unroll
    for (int c = 0; c < LOOPS; ++c) {
        const int i = g0 + c * stride;
        const int4 lv = lab4[i];
        float4 xv[D];
        #pragma unroll
        for (int d = 0; d < D; ++d) xv[d] = pred4[(size_t)d * n4 + i];
        const int labs[4] = {lv.x, lv.y, lv.z, lv.w};
        const float* xs = (const float*)&xv[0];
        #pragma unroll
        for (int p = 0; p < 4; ++p) {
            const int lab = labs[p];
            float sq = 0.f;
            #pragma unroll
            for (int d = 0; d < D; ++d) {
                const float df = mu[lab * D + d] - xs[d * 4 + p];
                sq = fmaf(df, df, sq);
            }
            const float h = fmaxf(sqrtf(sq) - DELTA_V, 0.f);
            const float h2 = h * h;
            #pragma unroll
            for (int k = 0; k < K; ++k)
                acc[k] += (lab == k) ? h2 : 0.f;
        }
    }

    const int wave = threadIdx.x >> 6, lane = threadIdx.x & 63;
    #pragma unroll
    for (int k = 0; k < K; ++k) {
        float v = acc[k];
        for (int off = 32; off > 0; off >>= 1) v += __shfl_down(v, off);
        if (lane == 0) lredW[wave][k] = v;
    }
    __syncthreads();
    if (threadIdx.x < K) {
        const int t = threadIdx.x;
        partials[t] = lredW[0][t] + lredW[1][t] + lredW[2][t] + lredW[3][t];
    }
}

__global__ __launch_bounds__(TPB)
void pass2_fused(const float* __restrict__ bl, const int* __restrict__ bL,
                 const float* __restrict__ il, const int* __restrict__ iL,
                 float* __restrict__ ws, int MN) {
    const int s = blockIdx.x / BPS, j = blockIdx.x % BPS;
    const int b = s & 3;
    const int n4 = MN >> 2;
    __shared__ float mu[30];
    __shared__ float lredW[4][6];
    const float* means = ws + MEAN_OFF + s * 30;
    float* partials = ws + P2_OFF + (size_t)(s * SLOTS + j) * 6;
    if (s < 4) pass2_body<2, 2>(bl + (size_t)b * 2 * MN, bL + (size_t)b * MN, means, partials, n4, mu, lredW);
    else       pass2_body<6, 5>(il + (size_t)b * 5 * MN, iL + (size_t)b * MN, means, partials, n4, mu, lredW);
}

// ---------------- Final: slot-parallel fold into 2 scalars ----------------
__global__ __launch_bounds__(TPB)
void final_kernel(const float* __restrict__ ws, float* __restrict__ out) {
    const int jj = threadIdx.x;
    const int wave = jj >> 6, lane = jj & 63;

    // preload: 48 independent scalar loads (8 slices x 6 vals from this thread's slot)
    float a[8][6];
    #pragma unroll
    for (int s2 = 0; s2 < 8; ++s2) {
        const float* P = ws + P2_OFF + (size_t)s2 * SLOTS * 6 + (size_t)jj * 6;
        #pragma unroll
        for (int k = 0; k < 6; ++k) a[s2][k] = (jj < SLOTS) ? P[k] : 0.f;
    }

    __shared__ float lredW[4][8][6];
    #pragma unroll
    for (int s2 = 0; s2 < 8; ++s2) {
        #pragma unroll
        for (int k = 0; k < 6; ++k) {
            float v = a[s2][k];
            for (int off = 32; off > 0; off >>= 1) v += __shfl_down(v, off);
            if (lane == 0) lredW[wave][s2][k] = v;
        }
    }
    __syncthreads();

    if (jj == 0) {
        float totB = 0.f, totI = 0.f;
        for (int s2 = 0; s2 < 8; ++s2) {
            const int Ks = (s2 < 4) ? 2 : 6;
            float lv = 0.f;
            for (int k = 0; k < Ks; ++k) {
                const float v = lredW[0][s2][k] + lredW[1][s2][k] + lredW[2][s2][k] + lredW[3][s2][k];
                lv += v / ws[CNT_OFF + s2 * 6 + k];
            }
            lv /= (float)Ks;
            const float loss = lv + ws[LDR_OFF + s2];
            if (s2 < 4) totB += loss; else totI += loss;
        }
        out[0] = totB * 0.25f;
        out[1] = totI * 0.25f;
    }
}

extern "C" void kernel_launch(void* const* d_in, const int* in_sizes, int n_in,
                              void* d_out, int out_size, void* d_ws, size_t ws_size,
                              hipStream_t stream) {
    const float* bin_logits  = (const float*)d_in[0];
    const int*   bin_labels  = (const int*)d_in[1];
    const float* inst_logits = (const float*)d_in[2];
    const int*   inst_labels = (const int*)d_in[3];
    float* ws  = (float*)d_ws;
    float* out = (float*)d_out;

    const int B  = 4;
    const int MN = in_sizes[1] / B;   // 524288

    pass1_fused<<<NBLK, TPB, 0, stream>>>(bin_logits, bin_labels, inst_logits, inst_labels, ws, MN);
    mid_kernel<<<8, TPB, 0, stream>>>(ws);
    pass2_fused<<<NBLK, TPB, 0, stream>>>(bin_logits, bin_labels, inst_logits, inst_labels, ws, MN);
    final_kernel<<<1, TPB, 0, stream>>>(ws, out);
}